// Round 1
// baseline (2375.968 us; speedup 1.0000x reference)
//
#include <hip/hip_runtime.h>
#include <math.h>

#define B_   8
#define T_   256
#define U_   64
#define UP1  65
#define DE   640
#define J_   512
#define V_   1024
#define LOG0 -1e30f

__device__ __forceinline__ float lae(float a, float b) {
    float m = fmaxf(a, b);
    float d = fminf(a, b) - m;          // <= 0
    return m + __logf(1.f + __expf(d)); // both -1e30: m + log(2), still ~-1e30
}

// ---------------- Kernel A: C[M x 512] = A[M x 640] * W[640 x 512] (+bias) -------------
__global__ __launch_bounds__(256) void gemm_in(const float* __restrict__ A,
                                               const float* __restrict__ W,
                                               const float* __restrict__ bias,
                                               float* __restrict__ C, int M) {
    __shared__ float As[16][64];
    __shared__ float Bs[16][64];
    int tid  = threadIdx.x;
    int row0 = blockIdx.x * 64;
    int col0 = blockIdx.y * 64;
    int tx = tid & 15, ty = tid >> 4;
    float acc[4][4] = {};
    int ar  = tid >> 2;  // A-tile row 0..63
    int akq = tid & 3;   // A k-quad
    int bkr = tid >> 4;  // B-tile k 0..15
    int bcq = tid & 15;  // B col-quad
    for (int k0 = 0; k0 < DE; k0 += 16) {
        float4 av = make_float4(0.f, 0.f, 0.f, 0.f);
        int arow = row0 + ar;
        if (arow < M) av = *(const float4*)&A[arow * DE + k0 + akq * 4];
        As[akq * 4 + 0][ar] = av.x;
        As[akq * 4 + 1][ar] = av.y;
        As[akq * 4 + 2][ar] = av.z;
        As[akq * 4 + 3][ar] = av.w;
        *(float4*)&Bs[bkr][bcq * 4] = *(const float4*)&W[(k0 + bkr) * J_ + col0 + bcq * 4];
        __syncthreads();
#pragma unroll
        for (int k = 0; k < 16; ++k) {
            float4 a4 = *(const float4*)&As[k][ty * 4];
            float4 b4 = *(const float4*)&Bs[k][tx * 4];
            float a[4] = {a4.x, a4.y, a4.z, a4.w};
            float b[4] = {b4.x, b4.y, b4.z, b4.w};
#pragma unroll
            for (int i = 0; i < 4; ++i)
#pragma unroll
                for (int j = 0; j < 4; ++j) acc[i][j] += a[i] * b[j];
        }
        __syncthreads();
    }
#pragma unroll
    for (int i = 0; i < 4; ++i) {
        int row = row0 + ty * 4 + i;
        if (row >= M) continue;
#pragma unroll
        for (int j = 0; j < 4; ++j) {
            int col = col0 + tx * 4 + j;
            float v = acc[i][j];
            if (bias) v += bias[col];
            C[row * J_ + col] = v;
        }
    }
}

// ------------- Kernel B: per-cell h=tanh(ep+pp), logits=h*Wout+bout, lse, gather -------
// 16 cells per 256-thread block; thread owns cols v = tid*4 .. tid*4+3.
__global__ __launch_bounds__(256) void joint_kernel(const float* __restrict__ ep,
                                                    const float* __restrict__ pp,
                                                    const float* __restrict__ Wout,
                                                    const float* __restrict__ bout,
                                                    const int* __restrict__ labels,
                                                    const int* __restrict__ pblank,
                                                    float* __restrict__ blp,
                                                    float* __restrict__ llp) {
    __shared__ float h[16][J_];
    __shared__ float red[4][16];
    __shared__ float Mrow[16];
    __shared__ float LSE[16];
    __shared__ int   binfo[16][4];  // b, t, u, label(-1 if u==U)

    int tid = threadIdx.x;
    int c0  = blockIdx.x * 16;
    if (tid < 16) {
        int c   = c0 + tid;
        int b   = c / (T_ * UP1);
        int rem = c % (T_ * UP1);
        int t   = rem / UP1;
        int u   = rem % UP1;
        binfo[tid][0] = b;
        binfo[tid][1] = t;
        binfo[tid][2] = u;
        binfo[tid][3] = (u < U_) ? labels[b * U_ + u] : -1;
    }
    __syncthreads();

    // stage h tile (tanh(ep+pp)); b_joint already folded into ep
    for (int r = 0; r < 16; ++r) {
        int b = binfo[r][0], t = binfo[r][1], u = binfo[r][2];
        const float* epr = &ep[(size_t)(b * T_ + t) * J_];
        const float* ppr = &pp[(size_t)(b * UP1 + u) * J_];
        int j = tid * 2;
        float2 e2 = *(const float2*)&epr[j];
        float2 p2 = *(const float2*)&ppr[j];
        float x0 = e2.x + p2.x, x1 = e2.y + p2.y;
        h[r][j]     = 1.f - 2.f / (__expf(2.f * x0) + 1.f);
        h[r][j + 1] = 1.f - 2.f / (__expf(2.f * x1) + 1.f);
    }
    __syncthreads();

    // logits GEMM: acc[r][c] = sum_k h[r][k] * Wout[k][tid*4+c]
    float acc[16][4] = {};
    const float* wbase = &Wout[tid * 4];
    for (int k0 = 0; k0 < J_; k0 += 4) {
        float4 w0 = *(const float4*)&wbase[(size_t)(k0 + 0) * V_];
        float4 w1 = *(const float4*)&wbase[(size_t)(k0 + 1) * V_];
        float4 w2 = *(const float4*)&wbase[(size_t)(k0 + 2) * V_];
        float4 w3 = *(const float4*)&wbase[(size_t)(k0 + 3) * V_];
#pragma unroll
        for (int r = 0; r < 16; ++r) {
            float4 h4 = *(const float4*)&h[r][k0];  // block-uniform -> LDS broadcast
            acc[r][0] += h4.x * w0.x + h4.y * w1.x + h4.z * w2.x + h4.w * w3.x;
            acc[r][1] += h4.x * w0.y + h4.y * w1.y + h4.z * w2.y + h4.w * w3.y;
            acc[r][2] += h4.x * w0.z + h4.y * w1.z + h4.z * w2.z + h4.w * w3.z;
            acc[r][3] += h4.x * w0.w + h4.y * w1.w + h4.z * w2.w + h4.w * w3.w;
        }
    }
    float4 bo = *(const float4*)&bout[tid * 4];
#pragma unroll
    for (int r = 0; r < 16; ++r) {
        acc[r][0] += bo.x; acc[r][1] += bo.y; acc[r][2] += bo.z; acc[r][3] += bo.w;
    }

    // per-row logsumexp over 1024 cols
    int lane = tid & 63, wv = tid >> 6;
#pragma unroll
    for (int r = 0; r < 16; ++r) {
        float m = fmaxf(fmaxf(acc[r][0], acc[r][1]), fmaxf(acc[r][2], acc[r][3]));
#pragma unroll
        for (int d = 1; d < 64; d <<= 1) m = fmaxf(m, __shfl_xor(m, d));
        if (lane == 0) red[wv][r] = m;
    }
    __syncthreads();
    if (tid < 16)
        Mrow[tid] = fmaxf(fmaxf(red[0][tid], red[1][tid]), fmaxf(red[2][tid], red[3][tid]));
    __syncthreads();
#pragma unroll
    for (int r = 0; r < 16; ++r) {
        float M = Mrow[r];
        float s = __expf(acc[r][0] - M) + __expf(acc[r][1] - M) +
                  __expf(acc[r][2] - M) + __expf(acc[r][3] - M);
#pragma unroll
        for (int d = 1; d < 64; d <<= 1) s += __shfl_xor(s, d);
        if (lane == 0) red[wv][r] = s;
    }
    __syncthreads();
    if (tid < 16)
        LSE[tid] = Mrow[tid] + __logf(red[0][tid] + red[1][tid] + red[2][tid] + red[3][tid]);
    __syncthreads();

    int blank = *pblank;
#pragma unroll
    for (int r = 0; r < 16; ++r) {
        int b = binfo[r][0], t = binfo[r][1], u = binfo[r][2], lab = binfo[r][3];
        float lse = LSE[r];
#pragma unroll
        for (int c4 = 0; c4 < 4; ++c4) {
            int v = tid * 4 + c4;
            if (v == blank) blp[(size_t)(b * T_ + t) * UP1 + u] = acc[r][c4] - lse;
            if (lab >= 0 && v == lab) llp[(size_t)(b * T_ + t) * U_ + u] = acc[r][c4] - lse;
        }
    }
}

// ---------------- Kernel C: alpha scan over T, one wave per batch element --------------
__global__ __launch_bounds__(512) void scan_kernel(const float* __restrict__ blp,
                                                   const float* __restrict__ llp,
                                                   const int* __restrict__ enc_lens,
                                                   const int* __restrict__ label_lens,
                                                   float* __restrict__ out) {
    __shared__ float lossArr[B_];
    int tid  = threadIdx.x;
    int b    = tid >> 6;
    int lane = tid & 63;
    int el = enc_lens[b];
    int ll = label_lens[b];
    float alpha   = (lane == 0) ? 0.f : LOG0;  // lane u holds alpha[u]
    float alpha64 = LOG0;                      // lane 63 additionally owns alpha[64]
    const float* bb = &blp[(size_t)b * T_ * UP1];
    const float* lb = &llp[(size_t)b * T_ * U_];

    for (int t = 0; t < T_; ++t) {
        if (t < el) {  // wave-uniform
            float bv   = bb[t * UP1 + lane];
            float bv64 = (lane == 63) ? bb[t * UP1 + 64] : 0.f;
            float lv   = lb[t * U_ + lane];
            // inclusive prefix sum of label logprobs
            float P = lv;
#pragma unroll
            for (int d = 1; d < 64; d <<= 1) {
                float v = __shfl(P, lane - d);
                if (lane >= d) P += v;
            }
            float L = __shfl(P, lane - 1);
            if (lane == 0) L = 0.f;
            float c = alpha + bv;
            float x = c - L;
            // inclusive logaddexp scan
            float s = x;
#pragma unroll
            for (int d = 1; d < 64; d <<= 1) {
                float v = __shfl(s, lane - d);
                if (lane >= d) s = lae(s, v);
            }
            // u = 64 element (lane 63): L[64] = P[63]
            float c64 = alpha64 + bv64;
            float x64 = c64 - P;
            float s64 = lae(s, x64);
            float a64 = P + s64;
            alpha = L + s;
            if (lane == 63) alpha64 = a64;
        }
    }

    float term  = bb[(el - 1) * UP1 + ll];
    float a_ll  = __shfl(alpha, (ll < 64) ? ll : 63);
    float a_64v = __shfl(alpha64, 63);
    float aU    = (ll < 64) ? a_ll : a_64v;
    if (lane == 0) lossArr[b] = -(aU + term);
    __syncthreads();
    if (tid == 0) {
        float s = 0.f;
        for (int i = 0; i < B_; ++i) s += lossArr[i];
        out[0] = s / (float)B_;
    }
}

extern "C" void kernel_launch(void* const* d_in, const int* in_sizes, int n_in,
                              void* d_out, int out_size, void* d_ws, size_t ws_size,
                              hipStream_t stream) {
    (void)in_sizes; (void)n_in; (void)out_size; (void)ws_size;
    const float* enc        = (const float*)d_in[0];
    const float* pred       = (const float*)d_in[1];
    const float* W_enc      = (const float*)d_in[2];
    const float* W_pred     = (const float*)d_in[3];
    const float* b_joint    = (const float*)d_in[4];
    const float* W_out      = (const float*)d_in[5];
    const float* b_out      = (const float*)d_in[6];
    const int*   labels     = (const int*)d_in[7];
    const int*   enc_lens   = (const int*)d_in[8];
    const int*   label_lens = (const int*)d_in[9];
    const int*   blank_id   = (const int*)d_in[10];

    float* ep  = (float*)d_ws;                      // B*T*J   = 1,048,576 f
    float* pp  = ep  + (size_t)B_ * T_ * J_;        // B*65*J  =   266,240 f
    float* blp = pp  + (size_t)B_ * UP1 * J_;       // B*T*65  =   133,120 f
    float* llp = blp + (size_t)B_ * T_ * UP1;       // B*T*64  =   131,072 f

    gemm_in<<<dim3((B_ * T_ + 63) / 64, J_ / 64), dim3(256), 0, stream>>>(
        enc, W_enc, b_joint, ep, B_ * T_);
    gemm_in<<<dim3((B_ * UP1 + 63) / 64, J_ / 64), dim3(256), 0, stream>>>(
        pred, W_pred, nullptr, pp, B_ * UP1);
    joint_kernel<<<dim3(B_ * T_ * UP1 / 16), dim3(256), 0, stream>>>(
        ep, pp, W_out, b_out, labels, blank_id, blp, llp);
    scan_kernel<<<dim3(1), dim3(512), 0, stream>>>(blp, llp, enc_lens, label_lens,
                                                   (float*)d_out);
}

// Round 2
// 798.064 us; speedup vs baseline: 2.9772x; 2.9772x over previous
//
#include <hip/hip_runtime.h>
#include <math.h>

#define B_   8
#define T_   256
#define U_   64
#define UP1  65
#define DE   640
#define J_   512
#define V_   1024
#define LOG0 -1e30f

typedef __attribute__((ext_vector_type(8))) short short8;
typedef __attribute__((ext_vector_type(4))) float f32x4;

__device__ __forceinline__ float lae(float a, float b) {
    float m = fmaxf(a, b);
    float d = fminf(a, b) - m;          // <= 0
    return m + __logf(1.f + __expf(d));
}

__device__ __forceinline__ unsigned short f2bf(float x) {
    union { float f; unsigned int u; } c; c.f = x;
    unsigned int r = (c.u + 0x7fffu + ((c.u >> 16) & 1u)) >> 16;  // RNE
    return (unsigned short)r;
}

// ---------------- Kernel A: C[M x 512] = A[M x 640] * W[640 x 512] (+bias) -------------
__global__ __launch_bounds__(256) void gemm_in(const float* __restrict__ A,
                                               const float* __restrict__ W,
                                               const float* __restrict__ bias,
                                               float* __restrict__ C, int M) {
    __shared__ float As[16][64];
    __shared__ float Bs[16][64];
    int tid  = threadIdx.x;
    int row0 = blockIdx.x * 64;
    int col0 = blockIdx.y * 64;
    int tx = tid & 15, ty = tid >> 4;
    float acc[4][4] = {};
    int ar  = tid >> 2;
    int akq = tid & 3;
    int bkr = tid >> 4;
    int bcq = tid & 15;
    for (int k0 = 0; k0 < DE; k0 += 16) {
        float4 av = make_float4(0.f, 0.f, 0.f, 0.f);
        int arow = row0 + ar;
        if (arow < M) av = *(const float4*)&A[arow * DE + k0 + akq * 4];
        As[akq * 4 + 0][ar] = av.x;
        As[akq * 4 + 1][ar] = av.y;
        As[akq * 4 + 2][ar] = av.z;
        As[akq * 4 + 3][ar] = av.w;
        *(float4*)&Bs[bkr][bcq * 4] = *(const float4*)&W[(k0 + bkr) * J_ + col0 + bcq * 4];
        __syncthreads();
#pragma unroll
        for (int k = 0; k < 16; ++k) {
            float4 a4 = *(const float4*)&As[k][ty * 4];
            float4 b4 = *(const float4*)&Bs[k][tx * 4];
            float a[4] = {a4.x, a4.y, a4.z, a4.w};
            float b[4] = {b4.x, b4.y, b4.z, b4.w};
#pragma unroll
            for (int i = 0; i < 4; ++i)
#pragma unroll
                for (int j = 0; j < 4; ++j) acc[i][j] += a[i] * b[j];
        }
        __syncthreads();
    }
#pragma unroll
    for (int i = 0; i < 4; ++i) {
        int row = row0 + ty * 4 + i;
        if (row >= M) continue;
#pragma unroll
        for (int j = 0; j < 4; ++j) {
            int col = col0 + tx * 4 + j;
            float v = acc[i][j];
            if (bias) v += bias[col];
            C[row * J_ + col] = v;
        }
    }
}

// -------- Kernel W: transpose + bf16-cast W_out[512][1024] -> Wt[1024][512] ------------
__global__ __launch_bounds__(256) void wt_kernel(const float* __restrict__ W,
                                                 unsigned short* __restrict__ Wt) {
    __shared__ float tile[32][33];
    int tx = threadIdx.x & 31, ty = threadIdx.x >> 5;  // 32x8
    int v0 = blockIdx.x * 32, k0 = blockIdx.y * 32;
#pragma unroll
    for (int i = 0; i < 4; ++i)
        tile[ty + i * 8][tx] = W[(size_t)(k0 + ty + i * 8) * V_ + v0 + tx];
    __syncthreads();
#pragma unroll
    for (int i = 0; i < 4; ++i)
        Wt[(size_t)(v0 + ty + i * 8) * J_ + k0 + tx] = f2bf(tile[tx][ty + i * 8]);
}

// -------- Kernel B: MFMA joint. 64 cells x 1024 cols x K=512 per block (8 waves) -------
// wave w owns cols [w*128, w*128+128): frags acc[mi(4)][ni(8)], 16x16x32 bf16 MFMA.
__global__ __launch_bounds__(512, 2) void joint_mfma(const float* __restrict__ ep,
                                                     const float* __restrict__ pp,
                                                     const unsigned short* __restrict__ Wt,
                                                     const float* __restrict__ bout,
                                                     const int* __restrict__ labels,
                                                     const int* __restrict__ pblank,
                                                     float* __restrict__ blp,
                                                     float* __restrict__ llp) {
    __shared__ __align__(16) unsigned char hB[64 * 1024];  // h[64][512] bf16, XOR-swizzled
    __shared__ float pm[8][64], ps[8][64], lseA[64];

    int tid = threadIdx.x;
    int c0  = blockIdx.x * 64;

    // ---- stage h = tanh(ep+pp) as bf16, swizzle byte ^= (row&7)<<4 ----
    {
        int row   = tid >> 3;
        int kslot = tid & 7;                    // 64 k-values per thread
        int cell  = c0 + row;
        int epRow = cell / UP1;
        int u     = cell - epRow * UP1;
        int b     = epRow >> 8;                 // T_=256
        const float* epr = ep + (size_t)epRow * J_ + kslot * 64;
        const float* ppr = pp + (size_t)(b * UP1 + u) * J_ + kslot * 64;
        unsigned swz     = ((unsigned)(row & 7)) << 4;
        unsigned rowbase = (unsigned)(row * 1024 + kslot * 128);
#pragma unroll
        for (int c8 = 0; c8 < 8; ++c8) {
            float4 e0 = *(const float4*)(epr + c8 * 8);
            float4 e1 = *(const float4*)(epr + c8 * 8 + 4);
            float4 p0 = *(const float4*)(ppr + c8 * 8);
            float4 p1 = *(const float4*)(ppr + c8 * 8 + 4);
            float x[8] = {e0.x + p0.x, e0.y + p0.y, e0.z + p0.z, e0.w + p0.w,
                          e1.x + p1.x, e1.y + p1.y, e1.z + p1.z, e1.w + p1.w};
            short8 hv;
#pragma unroll
            for (int j = 0; j < 8; ++j) {
                float e2 = __expf(2.f * x[j]);
                float t  = 1.f - 2.f / (e2 + 1.f);
                hv[j] = (short)f2bf(t);
            }
            *(short8*)(hB + ((rowbase + c8 * 16) ^ swz)) = hv;
        }
    }
    __syncthreads();

    int w = tid >> 6, lane = tid & 63;
    int lg = lane >> 4, ln = lane & 15;

    f32x4 acc[4][8] = {};

    for (int kt = 0; kt < 16; ++kt) {
        short8 bfrag[8];
#pragma unroll
        for (int ni = 0; ni < 8; ++ni)
            bfrag[ni] = *(const short8*)(Wt + (((size_t)(w * 128 + ni * 16 + ln)) << 9) +
                                         kt * 32 + lg * 8);
        short8 afrag[4];
#pragma unroll
        for (int mi = 0; mi < 4; ++mi) {
            int m = mi * 16 + ln;
            unsigned byteoff = (unsigned)(m * 1024) +
                               (((unsigned)(kt * 64 + lg * 16)) ^ (((unsigned)(m & 7)) << 4));
            afrag[mi] = *(const short8*)(hB + byteoff);
        }
#pragma unroll
        for (int mi = 0; mi < 4; ++mi)
#pragma unroll
            for (int ni = 0; ni < 8; ++ni)
                acc[mi][ni] = __builtin_amdgcn_mfma_f32_16x16x32_bf16(afrag[mi], bfrag[ni],
                                                                      acc[mi][ni], 0, 0, 0);
    }

    // bias
    float bo[8];
#pragma unroll
    for (int ni = 0; ni < 8; ++ni) bo[ni] = bout[w * 128 + ni * 16 + ln];
#pragma unroll
    for (int mi = 0; mi < 4; ++mi)
#pragma unroll
        for (int ni = 0; ni < 8; ++ni)
#pragma unroll
            for (int r = 0; r < 4; ++r) acc[mi][ni][r] += bo[ni];

    // per-wave partial row max / sumexp over this wave's 128 cols
#pragma unroll
    for (int mi = 0; mi < 4; ++mi) {
#pragma unroll
        for (int r = 0; r < 4; ++r) {
            float m = acc[mi][0][r];
#pragma unroll
            for (int ni = 1; ni < 8; ++ni) m = fmaxf(m, acc[mi][ni][r]);
            m = fmaxf(m, __shfl_xor(m, 1));
            m = fmaxf(m, __shfl_xor(m, 2));
            m = fmaxf(m, __shfl_xor(m, 4));
            m = fmaxf(m, __shfl_xor(m, 8));
            float s = 0.f;
#pragma unroll
            for (int ni = 0; ni < 8; ++ni) s += __expf(acc[mi][ni][r] - m);
            s += __shfl_xor(s, 1);
            s += __shfl_xor(s, 2);
            s += __shfl_xor(s, 4);
            s += __shfl_xor(s, 8);
            if (ln == 0) {
                int row = mi * 16 + lg * 4 + r;
                pm[w][row] = m;
                ps[w][row] = s;
            }
        }
    }
    __syncthreads();
    if (tid < 64) {
        float M = pm[0][tid];
#pragma unroll
        for (int w2 = 1; w2 < 8; ++w2) M = fmaxf(M, pm[w2][tid]);
        float S = 0.f;
#pragma unroll
        for (int w2 = 0; w2 < 8; ++w2) S += ps[w2][tid] * __expf(pm[w2][tid] - M);
        lseA[tid] = M + __logf(S);
    }
    __syncthreads();

    // gather blank & label logprobs
    int blank = *pblank;
#pragma unroll
    for (int mi = 0; mi < 4; ++mi) {
#pragma unroll
        for (int r = 0; r < 4; ++r) {
            int row   = mi * 16 + lg * 4 + r;
            int cell  = c0 + row;
            int epRow = cell / UP1;
            int u     = cell - epRow * UP1;
            int b     = epRow >> 8;
            int lab   = (u < U_) ? labels[(b << 6) + u] : -1;
            float lse = lseA[row];
#pragma unroll
            for (int ni = 0; ni < 8; ++ni) {
                int col  = (w << 7) + (ni << 4) + ln;
                float lp = acc[mi][ni][r] - lse;
                if (col == blank) blp[cell] = lp;
                if (col == lab)   llp[(size_t)((epRow << 6) + u)] = lp;
            }
        }
    }
}

// ---------------- Kernel C: alpha scan over T, one wave per batch element --------------
__global__ __launch_bounds__(512) void scan_kernel(const float* __restrict__ blp,
                                                   const float* __restrict__ llp,
                                                   const int* __restrict__ enc_lens,
                                                   const int* __restrict__ label_lens,
                                                   float* __restrict__ out) {
    __shared__ float lossArr[B_];
    int tid  = threadIdx.x;
    int b    = tid >> 6;
    int lane = tid & 63;
    int el = enc_lens[b];
    int ll = label_lens[b];
    float alpha   = (lane == 0) ? 0.f : LOG0;
    float alpha64 = LOG0;
    const float* bb = &blp[(size_t)b * T_ * UP1];
    const float* lb = &llp[(size_t)b * T_ * U_];

    for (int t = 0; t < T_; ++t) {
        if (t < el) {
            float bv   = bb[t * UP1 + lane];
            float bv64 = (lane == 63) ? bb[t * UP1 + 64] : 0.f;
            float lv   = lb[t * U_ + lane];
            float P = lv;
#pragma unroll
            for (int d = 1; d < 64; d <<= 1) {
                float v = __shfl(P, lane - d);
                if (lane >= d) P += v;
            }
            float L = __shfl(P, lane - 1);
            if (lane == 0) L = 0.f;
            float c = alpha + bv;
            float x = c - L;
            float s = x;
#pragma unroll
            for (int d = 1; d < 64; d <<= 1) {
                float v = __shfl(s, lane - d);
                if (lane >= d) s = lae(s, v);
            }
            float c64 = alpha64 + bv64;
            float x64 = c64 - P;
            float s64 = lae(s, x64);
            float a64 = P + s64;
            alpha = L + s;
            if (lane == 63) alpha64 = a64;
        }
    }

    float term  = bb[(el - 1) * UP1 + ll];
    float a_ll  = __shfl(alpha, (ll < 64) ? ll : 63);
    float a_64v = __shfl(alpha64, 63);
    float aU    = (ll < 64) ? a_ll : a_64v;
    if (lane == 0) lossArr[b] = -(aU + term);
    __syncthreads();
    if (tid == 0) {
        float s = 0.f;
        for (int i = 0; i < B_; ++i) s += lossArr[i];
        out[0] = s / (float)B_;
    }
}

extern "C" void kernel_launch(void* const* d_in, const int* in_sizes, int n_in,
                              void* d_out, int out_size, void* d_ws, size_t ws_size,
                              hipStream_t stream) {
    (void)in_sizes; (void)n_in; (void)out_size; (void)ws_size;
    const float* enc        = (const float*)d_in[0];
    const float* pred       = (const float*)d_in[1];
    const float* W_enc      = (const float*)d_in[2];
    const float* W_pred     = (const float*)d_in[3];
    const float* b_joint    = (const float*)d_in[4];
    const float* W_out      = (const float*)d_in[5];
    const float* b_out      = (const float*)d_in[6];
    const int*   labels     = (const int*)d_in[7];
    const int*   enc_lens   = (const int*)d_in[8];
    const int*   label_lens = (const int*)d_in[9];
    const int*   blank_id   = (const int*)d_in[10];

    float* ep  = (float*)d_ws;                      // B*T*J   = 1,048,576 f
    float* pp  = ep  + (size_t)B_ * T_ * J_;        // B*65*J  =   266,240 f
    float* blp = pp  + (size_t)B_ * UP1 * J_;       // B*T*65  =   133,120 f
    float* llp = blp + (size_t)B_ * T_ * UP1;       // B*T*64  =   131,072 f
    unsigned short* Wt = (unsigned short*)(llp + (size_t)B_ * T_ * U_);  // 1024x512 bf16

    wt_kernel<<<dim3(V_ / 32, J_ / 32), dim3(256), 0, stream>>>(W_out, Wt);
    gemm_in<<<dim3((B_ * T_ + 63) / 64, J_ / 64), dim3(256), 0, stream>>>(
        enc, W_enc, b_joint, ep, B_ * T_);
    gemm_in<<<dim3((B_ * UP1 + 63) / 64, J_ / 64), dim3(256), 0, stream>>>(
        pred, W_pred, nullptr, pp, B_ * UP1);
    joint_mfma<<<dim3(B_ * T_ * UP1 / 64), dim3(512), 0, stream>>>(
        ep, pp, Wt, b_out, labels, blank_id, blp, llp);
    scan_kernel<<<dim3(1), dim3(512), 0, stream>>>(blp, llp, enc_lens, label_lens,
                                                   (float*)d_out);
}